// Round 7
// baseline (198.376 us; speedup 1.0000x reference)
//
#include <hip/hip_runtime.h>
#include <hip/hip_fp16.h>

#define FH 240
#define FW 240
#define NSAMP 179   // 9 + 49 + 121
constexpr float IMG = 960.0f;

// ---------------- ws layout (floats) ----------------
static constexpr int WS_FMT   = 0;        // fmT fp16 [240][240][64] -> 1,843,200 float slots
static constexpr int WS_GPART = 1843200;  // gpartial [960][64]
static constexpr int WS_G     = 1904640;  // g [64] (pre-scaled by 1/57600)
static constexpr int WS_PERM  = 1904704;  // perm [4000] ints
static constexpr int WS_POOL  = 1908736;  // pooled [3n][64] ; hidg [128] right after

// ---------- Kernel 1: blocks 0..959 transpose fm -> fp16 fmT + channel partials;
//                      block 960: counting-sort boxes by (cy,cx) buckets -> perm ----------
__global__ __launch_bounds__(256) void k_prep(const float* __restrict__ fm,
                                              __half* __restrict__ fmT,
                                              float* __restrict__ gpartial,
                                              const float* __restrict__ boxes,
                                              int* __restrict__ perm, int n) {
    __shared__ float tile[64][65];
    __shared__ float red[4][64];
    __shared__ int hist[256];
    __shared__ int offs[256];
    int bid = blockIdx.x;
    int tid = threadIdx.x;

    if (bid < 960) {
        int y  = bid >> 2;
        int x0 = (bid & 3) * 64;
        int lane = tid & 63;
        int wv   = tid >> 6;
        int x = x0 + lane;
        bool xin = (x < FW);
        #pragma unroll
        for (int k = 0; k < 16; ++k) {
            int c = wv + k * 4;
            tile[c][lane] = xin ? fm[c * (FH * FW) + y * FW + x] : 0.0f;
        }
        __syncthreads();

        {   // parallel channel-partial: 256 threads sum 16 each, then 64 combine
            int c = tid & 63, q = tid >> 6;
            float s = 0.0f;
            #pragma unroll
            for (int i = 0; i < 16; ++i) s += tile[c][q * 16 + i];
            red[q][c] = s;
        }

        #pragma unroll
        for (int it = 0; it < 2; ++it) {
            int idx = tid + it * 256;       // 0..511
            int xl  = idx >> 3;             // 0..63
            int co  = (idx & 7) * 8;        // 0,8,...,56
            int xx  = x0 + xl;
            if (xx < FW) {
                union { float4 f4; __half2 h2[4]; } u;
                #pragma unroll
                for (int i = 0; i < 4; ++i)
                    u.h2[i] = __floats2half2_rn(tile[co + 2*i][xl], tile[co + 2*i + 1][xl]);
                *(float4*)&fmT[((size_t)(y * FW + xx)) * 64 + co] = u.f4;
            }
        }
        __syncthreads();
        if (tid < 64)
            gpartial[bid * 64 + tid] = red[0][tid] + red[1][tid] + red[2][tid] + red[3][tid];
    } else {
        // ---- counting sort of boxes by (cy, cx) 16x16 buckets ----
        hist[tid] = 0;
        __syncthreads();
        for (int i = tid; i < n; i += 256) {
            float cy = (boxes[i * 4 + 1] + boxes[i * 4 + 3]) * 0.5f;
            float cx = (boxes[i * 4 + 0] + boxes[i * 4 + 2]) * 0.5f;
            int by = min(15, max(0, (int)(cy * (16.0f / 960.0f))));
            int bx = min(15, max(0, (int)(cx * (16.0f / 960.0f))));
            atomicAdd(&hist[by * 16 + bx], 1);
        }
        __syncthreads();
        offs[tid] = hist[tid];
        __syncthreads();
        for (int st = 1; st < 256; st <<= 1) {
            int t2 = (tid >= st) ? offs[tid - st] : 0;
            __syncthreads();
            offs[tid] += t2;
            __syncthreads();
        }
        hist[tid] = offs[tid] - hist[tid];     // exclusive start per bucket
        __syncthreads();
        for (int i = tid; i < n; i += 256) {
            float cy = (boxes[i * 4 + 1] + boxes[i * 4 + 3]) * 0.5f;
            float cx = (boxes[i * 4 + 0] + boxes[i * 4 + 2]) * 0.5f;
            int by = min(15, max(0, (int)(cy * (16.0f / 960.0f))));
            int bx = min(15, max(0, (int)(cx * (16.0f / 960.0f))));
            int pos = atomicAdd(&hist[by * 16 + bx], 1);
            perm[pos] = i;
        }
    }
}

// ---------- Kernel 2: ROI bilinear pooling (unchanged from R6) ----------
__device__ __forceinline__ void acc8(float* a, const __half* __restrict__ base,
                                     int off, int c8, float w) {
    float4 raw = *(const float4*)(base + off + c8);   // 8 fp16
    const __half2* h = (const __half2*)&raw;
    #pragma unroll
    for (int i = 0; i < 4; ++i) {
        float2 f = __half22float2(h[i]);
        a[2*i]     = fmaf(w, f.x, a[2*i]);
        a[2*i + 1] = fmaf(w, f.y, a[2*i + 1]);
    }
}

__global__ __launch_bounds__(256) void k_pool(const __half* __restrict__ fmT,
                                              const float* __restrict__ boxes,
                                              const int* __restrict__ perm,
                                              const float* __restrict__ gpartial,
                                              float* __restrict__ g,
                                              float* __restrict__ pooled,
                                              const float* __restrict__ W1, const float* __restrict__ b1,
                                              const float* __restrict__ W2, const float* __restrict__ b2,
                                              const float* __restrict__ P1, const float* __restrict__ bp1,
                                              float* __restrict__ hidg) {
    __shared__ int   smp[NSAMP * 8];        // 5728 B
    __shared__ float part[64 * 33];         // 8448 B
    __shared__ float gsh[64];

    int tid = threadIdx.x;
    int bid = blockIdx.x;

    if (bid == 0) {
        int c = tid & 63, q = tid >> 6;
        float s = 0.0f;
        for (int i = q * 240; i < q * 240 + 240; ++i) s += gpartial[i * 64 + c];
        part[tid] = s;
        __syncthreads();
        if (tid < 64) {
            float v = (part[tid] + part[64 + tid] + part[128 + tid] + part[192 + tid]) * (1.0f / 57600.0f);
            g[tid] = v;
            gsh[tid] = v;
        }
        __syncthreads();
    }

    int box = perm[bid];

    // --- Phase 1: one thread per sample ---
    if (tid < NSAMP) {
        float bx1 = boxes[box * 4 + 0], by1 = boxes[box * 4 + 1];
        float bx2 = boxes[box * 4 + 2], by2 = boxes[box * 4 + 3];
        float x1n = (bx1 / IMG) * 2.0f - 1.0f;
        float y1n = (by1 / IMG) * 2.0f - 1.0f;
        float x2n = (bx2 / IMG) * 2.0f - 1.0f;
        float y2n = (by2 / IMG) * 2.0f - 1.0f;
        float cx = (x1n + x2n) * 0.5f, cy = (y1n + y2n) * 0.5f;
        float w2 = fmaxf(x2n - x1n, 1e-6f) * 0.5f;
        float h2 = fmaxf(y2n - y1n, 1e-6f) * 0.5f;
        int S, s, i;
        if (tid < 9)       { S = 3;  s = tid;      i = s / 3;  }
        else if (tid < 58) { S = 7;  s = tid - 9;  i = s / 7;  }
        else               { S = 11; s = tid - 58; i = s / 11; }
        int j = s - i * S;
        float Sf = (float)S;
        float bj = (2.0f * (float)j + 1.0f) / Sf - 1.0f;
        float bi = (2.0f * (float)i + 1.0f) / Sf - 1.0f;
        float gx = w2 * bj + cx;
        float gy = h2 * bi + cy;
        float ix = ((gx + 1.0f) * 240.0f - 1.0f) * 0.5f;
        float iy = ((gy + 1.0f) * 240.0f - 1.0f) * 0.5f;
        float x0f = floorf(ix), y0f = floorf(iy);
        float dx = ix - x0f,    dy = iy - y0f;
        int x0 = (int)x0f, y0 = (int)y0f;
        int x1 = x0 + 1,   y1 = y0 + 1;
        float inv = 1.0f / (Sf * Sf);
        float wx0 = (x0 >= 0 && x0 < FW) ? (1.0f - dx) : 0.0f;
        float wx1 = (x1 >= 0 && x1 < FW) ? dx          : 0.0f;
        float wy0 = (y0 >= 0 && y0 < FH) ? (1.0f - dy) : 0.0f;
        float wy1 = (y1 >= 0 && y1 < FH) ? dy          : 0.0f;
        int x0c = min(max(x0, 0), FW - 1), x1c = min(max(x1, 0), FW - 1);
        int y0c = min(max(y0, 0), FH - 1), y1c = min(max(y1, 0), FH - 1);
        int r0 = y0c * FW, r1 = y1c * FW;
        smp[tid * 8 + 0] = (r0 + x0c) * 64;
        smp[tid * 8 + 1] = (r0 + x1c) * 64;
        smp[tid * 8 + 2] = (r1 + x0c) * 64;
        smp[tid * 8 + 3] = (r1 + x1c) * 64;
        float* wp = (float*)&smp[tid * 8 + 4];
        wp[0] = wx0 * wy0 * inv;
        wp[1] = wx1 * wy0 * inv;
        wp[2] = wx0 * wy1 * inv;
        wp[3] = wx1 * wy1 * inv;
    }
    __syncthreads();

    // --- Phase 2: balanced gather. Slots 0-1: scale0, 2-10: scale1, 11-31: scale2 ---
    {
        int slot = tid >> 3, l = tid & 7, c8 = l << 3;
        int start, stride, end;
        if (slot < 2)       { start = slot;             stride = 2;  end = 9;     }
        else if (slot < 11) { start = 9 + (slot - 2);   stride = 9;  end = 58;    }
        else                { start = 58 + (slot - 11); stride = 21; end = NSAMP; }
        float a[8];
        #pragma unroll
        for (int k = 0; k < 8; ++k) a[k] = 0.0f;
        for (int s = start; s < end; s += stride) {
            int4   bo = *(const int4*)  &smp[s * 8];
            float4 wv = *(const float4*)&smp[s * 8 + 4];
            acc8(a, fmT, bo.x, c8, wv.x);
            acc8(a, fmT, bo.y, c8, wv.y);
            acc8(a, fmT, bo.z, c8, wv.z);
            acc8(a, fmT, bo.w, c8, wv.w);
        }
        #pragma unroll
        for (int i = 0; i < 8; ++i)
            part[(c8 + i) * 33 + slot] = a[i];
    }
    __syncthreads();

    // --- fused reduce: thread (sc,c) sums its scale's slot range ---
    if (tid < 192) {
        int sc = tid >> 6, c = tid & 63;
        int q0 = (sc == 0) ? 0 : (sc == 1) ? 2 : 11;
        int q1 = (sc == 0) ? 2 : (sc == 1) ? 11 : 32;
        float sum = 0.0f;
        for (int q = q0; q < q1; ++q) sum += part[c * 33 + q];
        pooled[(size_t)box * 192 + sc * 64 + c] = sum;
    }

    // ---- block 0 tail: g-head + fold its P1[192:256] contribution into hidg bias ----
    if (bid == 0) {
        __syncthreads();
        if (tid < 128) {                       // h1g = relu(g @ W1 + b1)
            float a = b1[tid];
            for (int k = 0; k < 64; ++k) a = fmaf(gsh[k], W1[k * 128 + tid], a);
            part[tid] = fmaxf(a, 0.0f);
        }
        __syncthreads();
        if (tid < 64) {                        // hg = relu(h1g @ W2 + b2)
            float a = b2[tid];
            for (int k = 0; k < 128; ++k) a = fmaf(part[k], W2[k * 64 + tid], a);
            part[128 + tid] = fmaxf(a, 0.0f);
        }
        __syncthreads();
        if (tid < 128) {                       // hidg = bp1 + hg @ P1[192:256]  (pre-relu bias)
            float a = bp1[tid];
            for (int k = 0; k < 64; ++k) a = fmaf(part[128 + k], P1[(192 + k) * 128 + tid], a);
            hidg[tid] = a;
        }
    }
}

// ---------- Kernel 3: FUSED heads + final MLP, v3 ----------
// R6 analysis: k_ht was latency/LDS-issue-bound at 1 block/CU (grid 250) with
// thin tiles (6.9 FMA per ds_read_b128) and 24 barriers nothing could overlap.
// v3: 8 boxes/block -> 500 blocks (~2 blocks/CU; LDS 51.9 KB caps 3) so one
// block's barriers/staging overlap the other's compute; fat register tiles
// (3rx8c / 2rx8c; ~2.3x fewer LDS reads); 32 KB weight chunks -> 6 chunks,
// ~13 barriers. Idle threads in S2-S4 are whole waves parked at the barrier.
__device__ __forceinline__ void stage32k(const float* __restrict__ src, float* dst, int tid) {
    #pragma unroll
    for (int j = 0; j < 8; ++j) {
        int idx = (tid + j * 256) * 4;
        *(float4*)&dst[idx] = *(const float4*)&src[idx];
    }
}

__global__ __launch_bounds__(256) void k_ht(const float* __restrict__ pooled,
                                            const float* __restrict__ hidg,
                                            const float* __restrict__ W1, const float* __restrict__ b1,
                                            const float* __restrict__ W2, const float* __restrict__ b2,
                                            const float* __restrict__ P1,
                                            const float* __restrict__ P2, const float* __restrict__ bp2,
                                            float* __restrict__ out, int n) {
    __shared__ float xc[1600];          // x[24][64] ; later cat[8][200] (192 used)
    __shared__ float h1[3168];          // h1[24][132] ; later hid[8][132]
    __shared__ float wb[8192];          // 32 KB weight chunk
    int tid = threadIdx.x;
    int box0 = blockIdx.x * 8;
    int nrows = 3 * n;

    // ---- stage x (24 rows x 16 float4) + chunk W1, one barrier ----
    for (int i = tid; i < 384; i += 256) {
        int r = i >> 4, q = (i & 15) * 4;
        int gr = 3 * box0 + r;
        float4 v = make_float4(0, 0, 0, 0);
        if (gr < nrows) v = *(const float4*)&pooled[(size_t)gr * 64 + q];
        *(float4*)&xc[r * 64 + q] = v;
    }
    stage32k(W1, wb, tid);
    __syncthreads();

    // ---- S1: h1 = relu(x @ W1 + b1)  [24x64]@[64x128]; 128 thr, tiles 3r x 8c ----
    if (tid < 128) {
        int cg = tid & 15, rg = tid >> 4;      // 16 cg x 8 rg
        int c8 = cg * 8, r3 = rg * 3;
        float acc[3][8] = {};
        #pragma unroll
        for (int k = 0; k < 64; k += 4) {
            float4 a[3];
            #pragma unroll
            for (int rr = 0; rr < 3; ++rr) a[rr] = *(const float4*)&xc[(r3 + rr) * 64 + k];
            #pragma unroll
            for (int kk = 0; kk < 4; ++kk) {
                float4 w0 = *(const float4*)&wb[(k + kk) * 128 + c8];
                float4 w1 = *(const float4*)&wb[(k + kk) * 128 + c8 + 4];
                #pragma unroll
                for (int rr = 0; rr < 3; ++rr) {
                    float av = ((const float*)&a[rr])[kk];
                    acc[rr][0] = fmaf(av, w0.x, acc[rr][0]);
                    acc[rr][1] = fmaf(av, w0.y, acc[rr][1]);
                    acc[rr][2] = fmaf(av, w0.z, acc[rr][2]);
                    acc[rr][3] = fmaf(av, w0.w, acc[rr][3]);
                    acc[rr][4] = fmaf(av, w1.x, acc[rr][4]);
                    acc[rr][5] = fmaf(av, w1.y, acc[rr][5]);
                    acc[rr][6] = fmaf(av, w1.z, acc[rr][6]);
                    acc[rr][7] = fmaf(av, w1.w, acc[rr][7]);
                }
            }
        }
        float4 b0 = *(const float4*)&b1[c8];
        float4 b1v = *(const float4*)&b1[c8 + 4];
        #pragma unroll
        for (int rr = 0; rr < 3; ++rr) {
            float4 o0, o1;
            o0.x = fmaxf(acc[rr][0] + b0.x, 0.0f);
            o0.y = fmaxf(acc[rr][1] + b0.y, 0.0f);
            o0.z = fmaxf(acc[rr][2] + b0.z, 0.0f);
            o0.w = fmaxf(acc[rr][3] + b0.w, 0.0f);
            o1.x = fmaxf(acc[rr][4] + b1v.x, 0.0f);
            o1.y = fmaxf(acc[rr][5] + b1v.y, 0.0f);
            o1.z = fmaxf(acc[rr][6] + b1v.z, 0.0f);
            o1.w = fmaxf(acc[rr][7] + b1v.w, 0.0f);
            *(float4*)&h1[(r3 + rr) * 132 + c8] = o0;
            *(float4*)&h1[(r3 + rr) * 132 + c8 + 4] = o1;
        }
    }
    __syncthreads();

    // ---- chunk W2 ----
    stage32k(W2, wb, tid);
    __syncthreads();

    // ---- S2: h2 = relu(h1 @ W2 + b2) -> cat  [24x128]@[128x64]; 64 thr, tiles 3r x 8c ----
    if (tid < 64) {
        int cg = tid & 7, rg = tid >> 3;       // 8 cg x 8 rg
        int c8 = cg * 8, r3 = rg * 3;
        float acc[3][8] = {};
        #pragma unroll
        for (int k = 0; k < 128; k += 4) {
            float4 a[3];
            #pragma unroll
            for (int rr = 0; rr < 3; ++rr) a[rr] = *(const float4*)&h1[(r3 + rr) * 132 + k];
            #pragma unroll
            for (int kk = 0; kk < 4; ++kk) {
                float4 w0 = *(const float4*)&wb[(k + kk) * 64 + c8];
                float4 w1 = *(const float4*)&wb[(k + kk) * 64 + c8 + 4];
                #pragma unroll
                for (int rr = 0; rr < 3; ++rr) {
                    float av = ((const float*)&a[rr])[kk];
                    acc[rr][0] = fmaf(av, w0.x, acc[rr][0]);
                    acc[rr][1] = fmaf(av, w0.y, acc[rr][1]);
                    acc[rr][2] = fmaf(av, w0.z, acc[rr][2]);
                    acc[rr][3] = fmaf(av, w0.w, acc[rr][3]);
                    acc[rr][4] = fmaf(av, w1.x, acc[rr][4]);
                    acc[rr][5] = fmaf(av, w1.y, acc[rr][5]);
                    acc[rr][6] = fmaf(av, w1.z, acc[rr][6]);
                    acc[rr][7] = fmaf(av, w1.w, acc[rr][7]);
                }
            }
        }
        float4 b0 = *(const float4*)&b2[c8];
        float4 b1v = *(const float4*)&b2[c8 + 4];
        #pragma unroll
        for (int rr = 0; rr < 3; ++rr) {       // row r3+rr = box rg, scale rr
            float4 o0, o1;
            o0.x = fmaxf(acc[rr][0] + b0.x, 0.0f);
            o0.y = fmaxf(acc[rr][1] + b0.y, 0.0f);
            o0.z = fmaxf(acc[rr][2] + b0.z, 0.0f);
            o0.w = fmaxf(acc[rr][3] + b0.w, 0.0f);
            o1.x = fmaxf(acc[rr][4] + b1v.x, 0.0f);
            o1.y = fmaxf(acc[rr][5] + b1v.y, 0.0f);
            o1.z = fmaxf(acc[rr][6] + b1v.z, 0.0f);
            o1.w = fmaxf(acc[rr][7] + b1v.w, 0.0f);
            *(float4*)&xc[rg * 200 + rr * 64 + c8] = o0;
            *(float4*)&xc[rg * 200 + rr * 64 + c8 + 4] = o1;
        }
    }
    __syncthreads();

    // ---- S3: hid = relu(cat @ P1[0:192] + hidg)  [8x192]@[192x128]
    //      3 chunks of 64 k; 64 thr, tiles 2r x 8c; acc persists across chunks ----
    float a3[2][8] = {};
    {
        int cg = tid & 15, rg = (tid >> 4) & 3;
        int c8 = cg * 8, r2 = rg * 2;
        #pragma unroll
        for (int ch = 0; ch < 3; ++ch) {
            stage32k(P1 + (size_t)ch * 64 * 128, wb, tid);
            __syncthreads();
            if (tid < 64) {
                #pragma unroll
                for (int k = 0; k < 64; k += 4) {
                    float4 a0 = *(const float4*)&xc[r2 * 200 + ch * 64 + k];
                    float4 a1 = *(const float4*)&xc[(r2 + 1) * 200 + ch * 64 + k];
                    #pragma unroll
                    for (int kk = 0; kk < 4; ++kk) {
                        float4 w0 = *(const float4*)&wb[(k + kk) * 128 + c8];
                        float4 w1 = *(const float4*)&wb[(k + kk) * 128 + c8 + 4];
                        float v0 = ((const float*)&a0)[kk];
                        float v1 = ((const float*)&a1)[kk];
                        a3[0][0] = fmaf(v0, w0.x, a3[0][0]);
                        a3[0][1] = fmaf(v0, w0.y, a3[0][1]);
                        a3[0][2] = fmaf(v0, w0.z, a3[0][2]);
                        a3[0][3] = fmaf(v0, w0.w, a3[0][3]);
                        a3[0][4] = fmaf(v0, w1.x, a3[0][4]);
                        a3[0][5] = fmaf(v0, w1.y, a3[0][5]);
                        a3[0][6] = fmaf(v0, w1.z, a3[0][6]);
                        a3[0][7] = fmaf(v0, w1.w, a3[0][7]);
                        a3[1][0] = fmaf(v1, w0.x, a3[1][0]);
                        a3[1][1] = fmaf(v1, w0.y, a3[1][1]);
                        a3[1][2] = fmaf(v1, w0.z, a3[1][2]);
                        a3[1][3] = fmaf(v1, w0.w, a3[1][3]);
                        a3[1][4] = fmaf(v1, w1.x, a3[1][4]);
                        a3[1][5] = fmaf(v1, w1.y, a3[1][5]);
                        a3[1][6] = fmaf(v1, w1.z, a3[1][6]);
                        a3[1][7] = fmaf(v1, w1.w, a3[1][7]);
                    }
                }
            }
            __syncthreads();
        }
        if (tid < 64) {                        // write hid (h1 region is dead)
            float4 h0 = *(const float4*)&hidg[c8];
            float4 h1v = *(const float4*)&hidg[c8 + 4];
            #pragma unroll
            for (int rr = 0; rr < 2; ++rr) {
                float4 o0, o1;
                o0.x = fmaxf(a3[rr][0] + h0.x, 0.0f);
                o0.y = fmaxf(a3[rr][1] + h0.y, 0.0f);
                o0.z = fmaxf(a3[rr][2] + h0.z, 0.0f);
                o0.w = fmaxf(a3[rr][3] + h0.w, 0.0f);
                o1.x = fmaxf(a3[rr][4] + h1v.x, 0.0f);
                o1.y = fmaxf(a3[rr][5] + h1v.y, 0.0f);
                o1.z = fmaxf(a3[rr][6] + h1v.z, 0.0f);
                o1.w = fmaxf(a3[rr][7] + h1v.w, 0.0f);
                *(float4*)&h1[(r2 + rr) * 132 + c8] = o0;
                *(float4*)&h1[(r2 + rr) * 132 + c8 + 4] = o1;
            }
        }
    }
    // ---- chunk P2 (concurrent with hid writes; different regions) ----
    stage32k(P2, wb, tid);
    __syncthreads();

    // ---- S4: out = relu(hid @ P2 + bp2)  [8x128]@[128x64]; 64 thr, tiles 2r x 4c ----
    if (tid < 64) {
        int cg = tid & 15, rg = tid >> 4;      // 16 cg x 4 rg
        int c4 = cg * 4, r2 = rg * 2;
        float acc[2][4] = {};
        #pragma unroll
        for (int k = 0; k < 128; k += 4) {
            float4 a0 = *(const float4*)&h1[r2 * 132 + k];
            float4 a1 = *(const float4*)&h1[(r2 + 1) * 132 + k];
            #pragma unroll
            for (int kk = 0; kk < 4; ++kk) {
                float4 w = *(const float4*)&wb[(k + kk) * 64 + c4];
                float v0 = ((const float*)&a0)[kk];
                float v1 = ((const float*)&a1)[kk];
                acc[0][0] = fmaf(v0, w.x, acc[0][0]);
                acc[0][1] = fmaf(v0, w.y, acc[0][1]);
                acc[0][2] = fmaf(v0, w.z, acc[0][2]);
                acc[0][3] = fmaf(v0, w.w, acc[0][3]);
                acc[1][0] = fmaf(v1, w.x, acc[1][0]);
                acc[1][1] = fmaf(v1, w.y, acc[1][1]);
                acc[1][2] = fmaf(v1, w.z, acc[1][2]);
                acc[1][3] = fmaf(v1, w.w, acc[1][3]);
            }
        }
        float4 bb = *(const float4*)&bp2[c4];
        #pragma unroll
        for (int rr = 0; rr < 2; ++rr) {
            int row = box0 + r2 + rr;
            if (row < n) {
                float4 o;
                o.x = fmaxf(acc[rr][0] + bb.x, 0.0f);
                o.y = fmaxf(acc[rr][1] + bb.y, 0.0f);
                o.z = fmaxf(acc[rr][2] + bb.z, 0.0f);
                o.w = fmaxf(acc[rr][3] + bb.w, 0.0f);
                *(float4*)&out[(size_t)row * 64 + c4] = o;
            }
        }
    }
}

extern "C" void kernel_launch(void* const* d_in, const int* in_sizes, int n_in,
                              void* d_out, int out_size, void* d_ws, size_t ws_size,
                              hipStream_t stream) {
    const float* fm    = (const float*)d_in[0];
    const float* boxes = (const float*)d_in[1];
    const float* W1    = (const float*)d_in[2];
    const float* b1    = (const float*)d_in[3];
    const float* W2    = (const float*)d_in[4];
    const float* b2    = (const float*)d_in[5];
    const float* P1    = (const float*)d_in[6];
    const float* bp1   = (const float*)d_in[7];
    const float* P2    = (const float*)d_in[8];
    const float* bp2   = (const float*)d_in[9];
    float* ws = (float*)d_ws;
    __half* fmT     = (__half*)(ws + WS_FMT);
    float* gpartial = ws + WS_GPART;
    float* g        = ws + WS_G;
    int*   perm     = (int*)(ws + WS_PERM);
    float* pooled   = ws + WS_POOL;
    float* out = (float*)d_out;
    int n = in_sizes[1] / 4;   // 4000 boxes
    int nrows = 3 * n;
    float* hidg = ws + WS_POOL + (size_t)nrows * 64;   // [128]

    k_prep<<<961, 256, 0, stream>>>(fm, fmT, gpartial, boxes, perm, n);
    k_pool<<<n, 256, 0, stream>>>(fmT, boxes, perm, gpartial, g, pooled,
                                  W1, b1, W2, b2, P1, bp1, hidg);
    k_ht<<<(n + 7) / 8, 256, 0, stream>>>(pooled, hidg, W1, b1, W2, b2,
                                          P1, P2, bp2, out, n);
}

// Round 8
// 130.845 us; speedup vs baseline: 1.5161x; 1.5161x over previous
//
#include <hip/hip_runtime.h>
#include <hip/hip_fp16.h>

#define FH 240
#define FW 240
#define NSAMP 179   // 9 + 49 + 121
constexpr float IMG = 960.0f;

// ---------------- ws layout (floats) ----------------
static constexpr int WS_FMT   = 0;        // fmT fp16 [240][240][64] -> 1,843,200 float slots
static constexpr int WS_GPART = 1843200;  // gpartial [960][64]
static constexpr int WS_G     = 1904640;  // g [64] (pre-scaled by 1/57600)
static constexpr int WS_PERM  = 1904704;  // perm [4000] ints
static constexpr int WS_POOL  = 1908736;  // pooled [3n][64] ; hidg [128] right after

// ---------- Kernel 1: blocks 0..959 transpose fm -> fp16 fmT + channel partials;
//                      block 960: counting-sort boxes by (cy,cx) buckets -> perm ----------
__global__ __launch_bounds__(256) void k_prep(const float* __restrict__ fm,
                                              __half* __restrict__ fmT,
                                              float* __restrict__ gpartial,
                                              const float* __restrict__ boxes,
                                              int* __restrict__ perm, int n) {
    __shared__ float tile[64][65];
    __shared__ float red[4][64];
    __shared__ int hist[256];
    __shared__ int offs[256];
    int bid = blockIdx.x;
    int tid = threadIdx.x;

    if (bid < 960) {
        int y  = bid >> 2;
        int x0 = (bid & 3) * 64;
        int lane = tid & 63;
        int wv   = tid >> 6;
        int x = x0 + lane;
        bool xin = (x < FW);
        #pragma unroll
        for (int k = 0; k < 16; ++k) {
            int c = wv + k * 4;
            tile[c][lane] = xin ? fm[c * (FH * FW) + y * FW + x] : 0.0f;
        }
        __syncthreads();

        {   // parallel channel-partial: 256 threads sum 16 each, then 64 combine
            int c = tid & 63, q = tid >> 6;
            float s = 0.0f;
            #pragma unroll
            for (int i = 0; i < 16; ++i) s += tile[c][q * 16 + i];
            red[q][c] = s;
        }

        #pragma unroll
        for (int it = 0; it < 2; ++it) {
            int idx = tid + it * 256;       // 0..511
            int xl  = idx >> 3;             // 0..63
            int co  = (idx & 7) * 8;        // 0,8,...,56
            int xx  = x0 + xl;
            if (xx < FW) {
                union { float4 f4; __half2 h2[4]; } u;
                #pragma unroll
                for (int i = 0; i < 4; ++i)
                    u.h2[i] = __floats2half2_rn(tile[co + 2*i][xl], tile[co + 2*i + 1][xl]);
                *(float4*)&fmT[((size_t)(y * FW + xx)) * 64 + co] = u.f4;
            }
        }
        __syncthreads();
        if (tid < 64)
            gpartial[bid * 64 + tid] = red[0][tid] + red[1][tid] + red[2][tid] + red[3][tid];
    } else {
        // ---- counting sort of boxes by (cy, cx) 16x16 buckets ----
        hist[tid] = 0;
        __syncthreads();
        for (int i = tid; i < n; i += 256) {
            float cy = (boxes[i * 4 + 1] + boxes[i * 4 + 3]) * 0.5f;
            float cx = (boxes[i * 4 + 0] + boxes[i * 4 + 2]) * 0.5f;
            int by = min(15, max(0, (int)(cy * (16.0f / 960.0f))));
            int bx = min(15, max(0, (int)(cx * (16.0f / 960.0f))));
            atomicAdd(&hist[by * 16 + bx], 1);
        }
        __syncthreads();
        offs[tid] = hist[tid];
        __syncthreads();
        for (int st = 1; st < 256; st <<= 1) {
            int t2 = (tid >= st) ? offs[tid - st] : 0;
            __syncthreads();
            offs[tid] += t2;
            __syncthreads();
        }
        hist[tid] = offs[tid] - hist[tid];     // exclusive start per bucket
        __syncthreads();
        for (int i = tid; i < n; i += 256) {
            float cy = (boxes[i * 4 + 1] + boxes[i * 4 + 3]) * 0.5f;
            float cx = (boxes[i * 4 + 0] + boxes[i * 4 + 2]) * 0.5f;
            int by = min(15, max(0, (int)(cy * (16.0f / 960.0f))));
            int bx = min(15, max(0, (int)(cx * (16.0f / 960.0f))));
            int pos = atomicAdd(&hist[by * 16 + bx], 1);
            perm[pos] = i;
        }
    }
}

// ---------- Kernel 2: ROI bilinear pooling (unchanged from R6, proven) ----------
__device__ __forceinline__ void acc8(float* a, const __half* __restrict__ base,
                                     int off, int c8, float w) {
    float4 raw = *(const float4*)(base + off + c8);   // 8 fp16
    const __half2* h = (const __half2*)&raw;
    #pragma unroll
    for (int i = 0; i < 4; ++i) {
        float2 f = __half22float2(h[i]);
        a[2*i]     = fmaf(w, f.x, a[2*i]);
        a[2*i + 1] = fmaf(w, f.y, a[2*i + 1]);
    }
}

__global__ __launch_bounds__(256) void k_pool(const __half* __restrict__ fmT,
                                              const float* __restrict__ boxes,
                                              const int* __restrict__ perm,
                                              const float* __restrict__ gpartial,
                                              float* __restrict__ g,
                                              float* __restrict__ pooled,
                                              const float* __restrict__ W1, const float* __restrict__ b1,
                                              const float* __restrict__ W2, const float* __restrict__ b2,
                                              const float* __restrict__ P1, const float* __restrict__ bp1,
                                              float* __restrict__ hidg) {
    __shared__ int   smp[NSAMP * 8];        // 5728 B
    __shared__ float part[64 * 33];         // 8448 B
    __shared__ float gsh[64];

    int tid = threadIdx.x;
    int bid = blockIdx.x;

    if (bid == 0) {
        int c = tid & 63, q = tid >> 6;
        float s = 0.0f;
        for (int i = q * 240; i < q * 240 + 240; ++i) s += gpartial[i * 64 + c];
        part[tid] = s;
        __syncthreads();
        if (tid < 64) {
            float v = (part[tid] + part[64 + tid] + part[128 + tid] + part[192 + tid]) * (1.0f / 57600.0f);
            g[tid] = v;
            gsh[tid] = v;
        }
        __syncthreads();
    }

    int box = perm[bid];

    // --- Phase 1: one thread per sample ---
    if (tid < NSAMP) {
        float bx1 = boxes[box * 4 + 0], by1 = boxes[box * 4 + 1];
        float bx2 = boxes[box * 4 + 2], by2 = boxes[box * 4 + 3];
        float x1n = (bx1 / IMG) * 2.0f - 1.0f;
        float y1n = (by1 / IMG) * 2.0f - 1.0f;
        float x2n = (bx2 / IMG) * 2.0f - 1.0f;
        float y2n = (by2 / IMG) * 2.0f - 1.0f;
        float cx = (x1n + x2n) * 0.5f, cy = (y1n + y2n) * 0.5f;
        float w2 = fmaxf(x2n - x1n, 1e-6f) * 0.5f;
        float h2 = fmaxf(y2n - y1n, 1e-6f) * 0.5f;
        int S, s, i;
        if (tid < 9)       { S = 3;  s = tid;      i = s / 3;  }
        else if (tid < 58) { S = 7;  s = tid - 9;  i = s / 7;  }
        else               { S = 11; s = tid - 58; i = s / 11; }
        int j = s - i * S;
        float Sf = (float)S;
        float bj = (2.0f * (float)j + 1.0f) / Sf - 1.0f;
        float bi = (2.0f * (float)i + 1.0f) / Sf - 1.0f;
        float gx = w2 * bj + cx;
        float gy = h2 * bi + cy;
        float ix = ((gx + 1.0f) * 240.0f - 1.0f) * 0.5f;
        float iy = ((gy + 1.0f) * 240.0f - 1.0f) * 0.5f;
        float x0f = floorf(ix), y0f = floorf(iy);
        float dx = ix - x0f,    dy = iy - y0f;
        int x0 = (int)x0f, y0 = (int)y0f;
        int x1 = x0 + 1,   y1 = y0 + 1;
        float inv = 1.0f / (Sf * Sf);
        float wx0 = (x0 >= 0 && x0 < FW) ? (1.0f - dx) : 0.0f;
        float wx1 = (x1 >= 0 && x1 < FW) ? dx          : 0.0f;
        float wy0 = (y0 >= 0 && y0 < FH) ? (1.0f - dy) : 0.0f;
        float wy1 = (y1 >= 0 && y1 < FH) ? dy          : 0.0f;
        int x0c = min(max(x0, 0), FW - 1), x1c = min(max(x1, 0), FW - 1);
        int y0c = min(max(y0, 0), FH - 1), y1c = min(max(y1, 0), FH - 1);
        int r0 = y0c * FW, r1 = y1c * FW;
        smp[tid * 8 + 0] = (r0 + x0c) * 64;
        smp[tid * 8 + 1] = (r0 + x1c) * 64;
        smp[tid * 8 + 2] = (r1 + x0c) * 64;
        smp[tid * 8 + 3] = (r1 + x1c) * 64;
        float* wp = (float*)&smp[tid * 8 + 4];
        wp[0] = wx0 * wy0 * inv;
        wp[1] = wx1 * wy0 * inv;
        wp[2] = wx0 * wy1 * inv;
        wp[3] = wx1 * wy1 * inv;
    }
    __syncthreads();

    // --- Phase 2: balanced gather. Slots 0-1: scale0, 2-10: scale1, 11-31: scale2 ---
    {
        int slot = tid >> 3, l = tid & 7, c8 = l << 3;
        int start, stride, end;
        if (slot < 2)       { start = slot;             stride = 2;  end = 9;     }
        else if (slot < 11) { start = 9 + (slot - 2);   stride = 9;  end = 58;    }
        else                { start = 58 + (slot - 11); stride = 21; end = NSAMP; }
        float a[8];
        #pragma unroll
        for (int k = 0; k < 8; ++k) a[k] = 0.0f;
        for (int s = start; s < end; s += stride) {
            int4   bo = *(const int4*)  &smp[s * 8];
            float4 wv = *(const float4*)&smp[s * 8 + 4];
            acc8(a, fmT, bo.x, c8, wv.x);
            acc8(a, fmT, bo.y, c8, wv.y);
            acc8(a, fmT, bo.z, c8, wv.z);
            acc8(a, fmT, bo.w, c8, wv.w);
        }
        #pragma unroll
        for (int i = 0; i < 8; ++i)
            part[(c8 + i) * 33 + slot] = a[i];
    }
    __syncthreads();

    // --- fused reduce: thread (sc,c) sums its scale's slot range ---
    if (tid < 192) {
        int sc = tid >> 6, c = tid & 63;
        int q0 = (sc == 0) ? 0 : (sc == 1) ? 2 : 11;
        int q1 = (sc == 0) ? 2 : (sc == 1) ? 11 : 32;
        float sum = 0.0f;
        for (int q = q0; q < q1; ++q) sum += part[c * 33 + q];
        pooled[(size_t)box * 192 + sc * 64 + c] = sum;
    }

    // ---- block 0 tail: g-head + fold its P1[192:256] contribution into hidg bias ----
    if (bid == 0) {
        __syncthreads();
        if (tid < 128) {                       // h1g = relu(g @ W1 + b1)
            float a = b1[tid];
            for (int k = 0; k < 64; ++k) a = fmaf(gsh[k], W1[k * 128 + tid], a);
            part[tid] = fmaxf(a, 0.0f);
        }
        __syncthreads();
        if (tid < 64) {                        // hg = relu(h1g @ W2 + b2)
            float a = b2[tid];
            for (int k = 0; k < 128; ++k) a = fmaf(part[k], W2[k * 64 + tid], a);
            part[128 + tid] = fmaxf(a, 0.0f);
        }
        __syncthreads();
        if (tid < 128) {                       // hidg = bp1 + hg @ P1[192:256]  (pre-relu bias)
            float a = bp1[tid];
            for (int k = 0; k < 64; ++k) a = fmaf(part[128 + k], P1[(192 + k) * 128 + tid], a);
            hidg[tid] = a;
        }
    }
}

// ---------- Kernel 3: FUSED heads + final MLP, v4 ----------
// R7 post-mortem: stride-8 col tiles -> 4-way LDS bank conflicts; 8-deep staging
// unroll + persistent fat acc -> VGPR 256 + scratch spill. v4 reverts to R6's
// proven instruction patterns (stride-4 conflict-free tiles, 2-float4/thread
// staging, acc<=8 regs) and changes ONLY geometry: 8 boxes/block -> 500 blocks
// = 2 blocks/CU (R6 had 250 blocks = 1/CU, nothing to overlap its 24 barriers).
// LDS: xc 1600 + h1 3168 + wb 4096 = 8864 floats = 35.5 KB.
__global__ __launch_bounds__(512) void k_ht(const float* __restrict__ pooled,
                                            const float* __restrict__ hidg,
                                            const float* __restrict__ W1, const float* __restrict__ b1,
                                            const float* __restrict__ W2, const float* __restrict__ b2,
                                            const float* __restrict__ P1,
                                            const float* __restrict__ P2, const float* __restrict__ bp2,
                                            float* __restrict__ out, int n) {
    __shared__ float xc[1600];          // x[24][64] ; later cat[8][200] (192 used)
    __shared__ float h1[3168];          // h1[24][132] ; later hid[8][132]
    __shared__ float wb[4096];          // 16 KB weight chunk
    int tid = threadIdx.x;
    int box0 = blockIdx.x * 8;
    int nrows = 3 * n;

    // ---- stage x: 24 rows x 16 float4 = 384 ----
    if (tid < 384) {
        int r = tid >> 4, q = (tid & 15) * 4;
        int gr = 3 * box0 + r;
        float4 v = make_float4(0, 0, 0, 0);
        if (gr < nrows) v = *(const float4*)&pooled[(size_t)gr * 64 + q];
        *(float4*)&xc[r * 64 + q] = v;
    }

    // ================= S1: h1 = relu(x @ W1 + b1)  [24x64]@[64x128], 2 chunks K=32 ====
    {
        int c4 = (tid & 31) * 4;           // 32 col-groups
        int rg = tid >> 5;                 // 16 row-groups; rg<12 own 2 rows
        int r2 = rg * 2;
        float acc[2][4] = {};
        #pragma unroll
        for (int ch = 0; ch < 2; ++ch) {
            __syncthreads();               // (ch0: x staged; ch1: wb reads done)
            for (int i = tid; i < 1024; i += 512) {         // W1 rows [ch*32, ch*32+32)
                int rr = i >> 5, qq = (i & 31) * 4;
                *(float4*)&wb[rr * 128 + qq] = *(const float4*)&W1[(size_t)(ch * 32 + rr) * 128 + qq];
            }
            __syncthreads();
            if (rg < 12) {
                int kb = ch * 32;
                #pragma unroll
                for (int k = 0; k < 32; k += 4) {
                    float4 a0 = *(const float4*)&xc[r2 * 64 + kb + k];
                    float4 a1 = *(const float4*)&xc[(r2 + 1) * 64 + kb + k];
                    #pragma unroll
                    for (int kk = 0; kk < 4; ++kk) {
                        float4 w = *(const float4*)&wb[(k + kk) * 128 + c4];
                        float v0 = ((const float*)&a0)[kk];
                        float v1 = ((const float*)&a1)[kk];
                        acc[0][0] = fmaf(v0, w.x, acc[0][0]);
                        acc[0][1] = fmaf(v0, w.y, acc[0][1]);
                        acc[0][2] = fmaf(v0, w.z, acc[0][2]);
                        acc[0][3] = fmaf(v0, w.w, acc[0][3]);
                        acc[1][0] = fmaf(v1, w.x, acc[1][0]);
                        acc[1][1] = fmaf(v1, w.y, acc[1][1]);
                        acc[1][2] = fmaf(v1, w.z, acc[1][2]);
                        acc[1][3] = fmaf(v1, w.w, acc[1][3]);
                    }
                }
            }
        }
        if (rg < 12) {
            float4 bb = *(const float4*)&b1[c4];
            #pragma unroll
            for (int rr = 0; rr < 2; ++rr) {
                float4 o;
                o.x = fmaxf(acc[rr][0] + bb.x, 0.0f);
                o.y = fmaxf(acc[rr][1] + bb.y, 0.0f);
                o.z = fmaxf(acc[rr][2] + bb.z, 0.0f);
                o.w = fmaxf(acc[rr][3] + bb.w, 0.0f);
                *(float4*)&h1[(r2 + rr) * 132 + c4] = o;
            }
        }
    }

    // ================= S2: h2 = relu(h1 @ W2 + b2) -> cat  [24x128]@[128x64], 2 chunks K=64 ====
    {
        int c4 = (tid & 15) * 4;           // 16 col-groups
        int rg = tid >> 4;                 // 32 row-groups; rg<12 own 2 rows
        int r2 = rg * 2;
        float acc[2][4] = {};
        #pragma unroll
        for (int ch = 0; ch < 2; ++ch) {
            __syncthreads();               // h1 writes visible / wb reads done
            for (int i = tid; i < 1024; i += 512) {         // W2 rows [ch*64, ch*64+64)
                int rr = i >> 4, qq = (i & 15) * 4;
                *(float4*)&wb[rr * 64 + qq] = *(const float4*)&W2[(size_t)(ch * 64 + rr) * 64 + qq];
            }
            __syncthreads();
            if (rg < 12) {
                int kb = ch * 64;
                #pragma unroll
                for (int k = 0; k < 64; k += 4) {
                    float4 a0 = *(const float4*)&h1[r2 * 132 + kb + k];
                    float4 a1 = *(const float4*)&h1[(r2 + 1) * 132 + kb + k];
                    #pragma unroll
                    for (int kk = 0; kk < 4; ++kk) {
                        float4 w = *(const float4*)&wb[(k + kk) * 64 + c4];
                        float v0 = ((const float*)&a0)[kk];
                        float v1 = ((const float*)&a1)[kk];
                        acc[0][0] = fmaf(v0, w.x, acc[0][0]);
                        acc[0][1] = fmaf(v0, w.y, acc[0][1]);
                        acc[0][2] = fmaf(v0, w.z, acc[0][2]);
                        acc[0][3] = fmaf(v0, w.w, acc[0][3]);
                        acc[1][0] = fmaf(v1, w.x, acc[1][0]);
                        acc[1][1] = fmaf(v1, w.y, acc[1][1]);
                        acc[1][2] = fmaf(v1, w.z, acc[1][2]);
                        acc[1][3] = fmaf(v1, w.w, acc[1][3]);
                    }
                }
            }
        }
        __syncthreads();                   // all h1/xc reads done -> safe to write cat
        if (rg < 12) {
            float4 bb = *(const float4*)&b2[c4];
            #pragma unroll
            for (int rr = 0; rr < 2; ++rr) {
                int r = r2 + rr;                      // 0..23
                int b = r / 3, sc = r - b * 3;
                float4 o;
                o.x = fmaxf(acc[rr][0] + bb.x, 0.0f);
                o.y = fmaxf(acc[rr][1] + bb.y, 0.0f);
                o.z = fmaxf(acc[rr][2] + bb.z, 0.0f);
                o.w = fmaxf(acc[rr][3] + bb.w, 0.0f);
                *(float4*)&xc[b * 200 + sc * 64 + c4] = o;   // cat row b
            }
        }
    }

    // ================= S3: hid = relu(cat @ P1[0:192] + hidg)  [8x192]@[192x128], 6 chunks K=32 ====
    {
        int c4 = (tid & 31) * 4;           // 32 col-groups
        int rg = tid >> 5;                 // 16; rg<4 own 2 rows
        int r2 = rg * 2;
        float acc[2][4] = {};
        #pragma unroll
        for (int ch = 0; ch < 6; ++ch) {
            __syncthreads();               // cat writes visible / wb reads done
            for (int i = tid; i < 1024; i += 512) {         // P1 rows [ch*32, ch*32+32)
                int rr = i >> 5, qq = (i & 31) * 4;
                *(float4*)&wb[rr * 128 + qq] = *(const float4*)&P1[(size_t)(ch * 32 + rr) * 128 + qq];
            }
            __syncthreads();
            if (rg < 4) {
                int kb = ch * 32;
                #pragma unroll
                for (int k = 0; k < 32; k += 4) {
                    float4 a0 = *(const float4*)&xc[r2 * 200 + kb + k];
                    float4 a1 = *(const float4*)&xc[(r2 + 1) * 200 + kb + k];
                    #pragma unroll
                    for (int kk = 0; kk < 4; ++kk) {
                        float4 w = *(const float4*)&wb[(k + kk) * 128 + c4];
                        float v0 = ((const float*)&a0)[kk];
                        float v1 = ((const float*)&a1)[kk];
                        acc[0][0] = fmaf(v0, w.x, acc[0][0]);
                        acc[0][1] = fmaf(v0, w.y, acc[0][1]);
                        acc[0][2] = fmaf(v0, w.z, acc[0][2]);
                        acc[0][3] = fmaf(v0, w.w, acc[0][3]);
                        acc[1][0] = fmaf(v1, w.x, acc[1][0]);
                        acc[1][1] = fmaf(v1, w.y, acc[1][1]);
                        acc[1][2] = fmaf(v1, w.z, acc[1][2]);
                        acc[1][3] = fmaf(v1, w.w, acc[1][3]);
                    }
                }
            }
        }
        __syncthreads();                   // h1 reads (S2) long done -> safe to write hid
        if (rg < 4) {
            float4 hb = *(const float4*)&hidg[c4];
            #pragma unroll
            for (int rr = 0; rr < 2; ++rr) {
                float4 o;
                o.x = fmaxf(acc[rr][0] + hb.x, 0.0f);
                o.y = fmaxf(acc[rr][1] + hb.y, 0.0f);
                o.z = fmaxf(acc[rr][2] + hb.z, 0.0f);
                o.w = fmaxf(acc[rr][3] + hb.w, 0.0f);
                *(float4*)&h1[(r2 + rr) * 132 + c4] = o;   // hid row
            }
        }
    }

    // ================= S4: out = relu(hid @ P2 + bp2)  [8x128]@[128x64], 2 chunks K=64 ====
    {
        int c4 = (tid & 15) * 4;           // 16 col-groups
        int r  = tid >> 4;                 // 32; r<8 own 1 row
        float acc[4] = {};
        #pragma unroll
        for (int ch = 0; ch < 2; ++ch) {
            __syncthreads();               // hid writes visible / wb reads done
            for (int i = tid; i < 1024; i += 512) {         // P2 rows [ch*64, ch*64+64)
                int rr = i >> 4, qq = (i & 15) * 4;
                *(float4*)&wb[rr * 64 + qq] = *(const float4*)&P2[(size_t)(ch * 64 + rr) * 64 + qq];
            }
            __syncthreads();
            if (r < 8) {
                int kb = ch * 64;
                #pragma unroll
                for (int k = 0; k < 64; k += 4) {
                    float4 a = *(const float4*)&h1[r * 132 + kb + k];
                    #pragma unroll
                    for (int kk = 0; kk < 4; ++kk) {
                        float4 w = *(const float4*)&wb[(k + kk) * 64 + c4];
                        float av = ((const float*)&a)[kk];
                        acc[0] = fmaf(av, w.x, acc[0]);
                        acc[1] = fmaf(av, w.y, acc[1]);
                        acc[2] = fmaf(av, w.z, acc[2]);
                        acc[3] = fmaf(av, w.w, acc[3]);
                    }
                }
            }
        }
        if (r < 8) {
            int row = box0 + r;
            if (row < n) {
                float4 bb = *(const float4*)&bp2[c4];
                float4 o;
                o.x = fmaxf(acc[0] + bb.x, 0.0f);
                o.y = fmaxf(acc[1] + bb.y, 0.0f);
                o.z = fmaxf(acc[2] + bb.z, 0.0f);
                o.w = fmaxf(acc[3] + bb.w, 0.0f);
                *(float4*)&out[(size_t)row * 64 + c4] = o;
            }
        }
    }
}

extern "C" void kernel_launch(void* const* d_in, const int* in_sizes, int n_in,
                              void* d_out, int out_size, void* d_ws, size_t ws_size,
                              hipStream_t stream) {
    const float* fm    = (const float*)d_in[0];
    const float* boxes = (const float*)d_in[1];
    const float* W1    = (const float*)d_in[2];
    const float* b1    = (const float*)d_in[3];
    const float* W2    = (const float*)d_in[4];
    const float* b2    = (const float*)d_in[5];
    const float* P1    = (const float*)d_in[6];
    const float* bp1   = (const float*)d_in[7];
    const float* P2    = (const float*)d_in[8];
    const float* bp2   = (const float*)d_in[9];
    float* ws = (float*)d_ws;
    __half* fmT     = (__half*)(ws + WS_FMT);
    float* gpartial = ws + WS_GPART;
    float* g        = ws + WS_G;
    int*   perm     = (int*)(ws + WS_PERM);
    float* pooled   = ws + WS_POOL;
    float* out = (float*)d_out;
    int n = in_sizes[1] / 4;   // 4000 boxes
    int nrows = 3 * n;
    float* hidg = ws + WS_POOL + (size_t)nrows * 64;   // [128]

    k_prep<<<961, 256, 0, stream>>>(fm, fmT, gpartial, boxes, perm, n);
    k_pool<<<n, 256, 0, stream>>>(fmT, boxes, perm, gpartial, g, pooled,
                                  W1, b1, W2, b2, P1, bp1, hidg);
    k_ht<<<(n + 7) / 8, 512, 0, stream>>>(pooled, hidg, W1, b1, W2, b2,
                                          P1, P2, bp2, out, n);
}